// Round 1
// baseline (5213.594 us; speedup 1.0000x reference)
//
#include <hip/hip_runtime.h>
#include <math.h>

#define NN 50000
#define EE 1600000
#define FN 92
#define FE 41
#define CC 128
#define LL 3
#define GG 256
#define ZDIM 297   // 2C + F_EDGE

__device__ __forceinline__ float softplus_f(float x) {
    return fmaxf(x, 0.0f) + log1pf(__expf(-fabsf(x)));
}
__device__ __forceinline__ float sigmoid_f(float x) {
    return 1.0f / (1.0f + __expf(-x));
}

// ---------------------------------------------------------------------------
// Generic row-major GEMM: C[M][NC] = act(A[M][lda] (K cols used) @ B[Kpad][NC] + bias)
// Tile: 64 rows x 128 cols, KC=32, block 256 threads, 8x4 micro-tile.
// ---------------------------------------------------------------------------
template<int ACT>
__global__ __launch_bounds__(256)
void gemm_rt(const float* __restrict__ A, const float* __restrict__ B,
             float* __restrict__ C, const float* __restrict__ bias,
             int M, int K, int lda, int NC) {
    __shared__ float As[32][68];     // [k][row], padded
    __shared__ float Bs[32 * 128];   // [k][col]
    int tid = threadIdx.x;
    int colTiles = NC >> 7;
    int rowTile = blockIdx.x / colTiles;
    int colTile = blockIdx.x - rowTile * colTiles;
    int row0 = rowTile * 64;
    int c0 = colTile * 128;
    int ty = tid >> 5;     // 0..7  -> 8 rows each
    int tx = tid & 31;     // 0..31 -> 4 cols each

    float acc[8][4];
#pragma unroll
    for (int i = 0; i < 8; i++)
#pragma unroll
        for (int j = 0; j < 4; j++) acc[i][j] = 0.f;

    int nChunks = (K + 31) >> 5;
    for (int ch = 0; ch < nChunks; ch++) {
        int k0 = ch << 5;
        // stage A (transposed into LDS): 64 rows x 32 k
#pragma unroll
        for (int t = 0; t < 8; t++) {
            int idx = tid + t * 256;       // 0..2047
            int r = idx >> 5;              // 0..63
            int kk = idx & 31;
            int grow = row0 + r;
            int gk = k0 + kk;
            float v = 0.f;
            if (grow < M && gk < K) v = A[(long)grow * lda + gk];
            As[kk][r] = v;
        }
        // stage B: 32 x 128, float4
        const float* Bg = B + (long)k0 * NC + c0;
#pragma unroll
        for (int t = 0; t < 4; t++) {
            int f4 = tid + t * 256;        // 0..1023
            int kk = f4 >> 5;
            int j = (f4 & 31) << 2;
            float4 v = *(const float4*)(Bg + (long)kk * NC + j);
            *(float4*)(&Bs[kk * 128 + j]) = v;
        }
        __syncthreads();
#pragma unroll
        for (int kk = 0; kk < 32; kk++) {
            float4 a0 = *(const float4*)(&As[kk][ty * 8]);
            float4 a1 = *(const float4*)(&As[kk][ty * 8 + 4]);
            float4 b  = *(const float4*)(&Bs[kk * 128 + tx * 4]);
            float av[8] = {a0.x, a0.y, a0.z, a0.w, a1.x, a1.y, a1.z, a1.w};
            float bv[4] = {b.x, b.y, b.z, b.w};
#pragma unroll
            for (int i = 0; i < 8; i++)
#pragma unroll
                for (int j = 0; j < 4; j++)
                    acc[i][j] = fmaf(av[i], bv[j], acc[i][j]);
        }
        __syncthreads();
    }
    // epilogue
    float bv[4] = {0.f, 0.f, 0.f, 0.f};
    if (bias) {
#pragma unroll
        for (int j = 0; j < 4; j++) bv[j] = bias[c0 + tx * 4 + j];
    }
#pragma unroll
    for (int i = 0; i < 8; i++) {
        int grow = row0 + ty * 8 + i;
        if (grow < M) {
            float4 o;
            float r0 = acc[i][0] + bv[0];
            float r1 = acc[i][1] + bv[1];
            float r2 = acc[i][2] + bv[2];
            float r3 = acc[i][3] + bv[3];
            if (ACT) { r0 = softplus_f(r0); r1 = softplus_f(r1);
                       r2 = softplus_f(r2); r3 = softplus_f(r3); }
            o.x = r0; o.y = r1; o.z = r2; o.w = r3;
            *(float4*)(&C[(long)grow * NC + c0 + tx * 4]) = o;
        }
    }
}

// Build WB[128][512]: col j<128: Wf[j][k]; 128..255: Ws[j-128][k];
// 256..383: Wf[j-256][128+k]; 384..511: Ws[j-384][128+k]
__global__ void build_WB(const float* __restrict__ Wf, const float* __restrict__ Ws,
                         float* __restrict__ WB) {
    int idx = blockIdx.x * blockDim.x + threadIdx.x;
    if (idx >= 128 * 512) return;
    int k = idx >> 9;
    int j = idx & 511;
    float v;
    if (j < 128)      v = Wf[j * ZDIM + k];
    else if (j < 256) v = Ws[(j - 128) * ZDIM + k];
    else if (j < 384) v = Wf[(j - 256) * ZDIM + 128 + k];
    else              v = Ws[(j - 384) * ZDIM + 128 + k];
    WB[idx] = v;
}

// WT[Kpad][C] = W[C][K]^T zero-padded in k
__global__ void transpose_pad(const float* __restrict__ W, float* __restrict__ WT,
                              int C_, int K_, int Kpad) {
    int idx = blockIdx.x * blockDim.x + threadIdx.x;
    if (idx >= Kpad * C_) return;
    int k = idx / C_;
    int c = idx - k * C_;
    WT[idx] = (k < K_) ? W[c * K_ + k] : 0.f;
}

// ---------------------------------------------------------------------------
// Edge gate: f = P[dst][c] + P[src][256+c] + ea.Wf_e[c] + bf[c]
//            s = P[dst][128+c] + P[src][384+c] + ea.Ws_e[c] + bs[c]
//            m = sigmoid(f)*softplus(s); agg[dst][c] += m
// Block 256 = 2 edge slots x 128 channels. Weight cols in registers.
// ---------------------------------------------------------------------------
#define ETILE 16
__global__ __launch_bounds__(256)
void edge_gate(const float* __restrict__ P, const float* __restrict__ ea,
               const int* __restrict__ srcI, const int* __restrict__ dstI,
               const float* __restrict__ Wf, const float* __restrict__ Ws,
               const float* __restrict__ bf, const float* __restrict__ bs,
               float* __restrict__ agg) {
    __shared__ float ea_s[ETILE * 44];
    __shared__ int src_s[ETILE], dst_s[ETILE];
    int tid = threadIdx.x;
    int c = tid & 127;
    int slot = tid >> 7;

    float wfr[44], wsr[44];
#pragma unroll
    for (int k = 0; k < 44; k++) {
        wfr[k] = (k < FE) ? Wf[c * ZDIM + 256 + k] : 0.f;
        wsr[k] = (k < FE) ? Ws[c * ZDIM + 256 + k] : 0.f;
    }
    float bfc = bf[c], bsc = bs[c];

    for (long e0 = (long)blockIdx.x * ETILE; e0 < (long)EE;
         e0 += (long)gridDim.x * ETILE) {
        __syncthreads();
        for (int idx = tid; idx < ETILE * 44; idx += 256) {
            int i = idx / 44;
            int k = idx - i * 44;
            long e = e0 + i;
            ea_s[idx] = (k < FE && e < (long)EE) ? ea[e * FE + k] : 0.f;
        }
        if (tid < ETILE) {
            long e = e0 + tid;
            src_s[tid] = (e < (long)EE) ? srcI[e] : 0;
            dst_s[tid] = (e < (long)EE) ? dstI[e] : 0;
        }
        __syncthreads();
        for (int t = 0; t < ETILE / 2; t++) {
            int i = t * 2 + slot;
            long e = e0 + i;
            if (e >= (long)EE) continue;
            int d = dst_s[i], sv = src_s[i];
            const float* Pd = P + (long)d * 512;
            const float* Psrc = P + (long)sv * 512 + 256;
            float f = Pd[c] + Psrc[c] + bfc;
            float s = Pd[128 + c] + Psrc[128 + c] + bsc;
            const float4* e4 = (const float4*)(&ea_s[i * 44]);
#pragma unroll
            for (int k4 = 0; k4 < 11; k4++) {
                float4 v = e4[k4];
                f = fmaf(v.x, wfr[k4 * 4 + 0], f); s = fmaf(v.x, wsr[k4 * 4 + 0], s);
                f = fmaf(v.y, wfr[k4 * 4 + 1], f); s = fmaf(v.y, wsr[k4 * 4 + 1], s);
                f = fmaf(v.z, wfr[k4 * 4 + 2], f); s = fmaf(v.z, wsr[k4 * 4 + 2], s);
                f = fmaf(v.w, wfr[k4 * 4 + 3], f); s = fmaf(v.w, wsr[k4 * 4 + 3], s);
            }
            float m = sigmoid_f(f) * softplus_f(s);
            atomicAdd(&agg[(long)d * CC + c], m);
        }
    }
}

__global__ void residual_softplus(float* __restrict__ out, const float* __restrict__ agg) {
    int idx = blockIdx.x * blockDim.x + threadIdx.x;
    if (idx < NN * CC / 4) {
        float4 o = ((const float4*)out)[idx];
        float4 a = ((const float4*)agg)[idx];
        o.x = softplus_f(o.x + a.x);
        o.y = softplus_f(o.y + a.y);
        o.z = softplus_f(o.z + a.z);
        o.w = softplus_f(o.w + a.w);
        ((float4*)out)[idx] = o;
    }
}

__global__ void pool_accum(const float* __restrict__ post, const int* __restrict__ batch,
                           float* __restrict__ sums, float* __restrict__ cnt) {
    int idx = blockIdx.x * blockDim.x + threadIdx.x;
    if (idx >= NN * CC) return;
    int n = idx >> 7;
    int c = idx & 127;
    int g = batch[n];
    atomicAdd(&sums[g * CC + c], post[idx]);
    if (c == 0) atomicAdd(&cnt[g], 1.0f);
}

__global__ void pool_head(const float* __restrict__ sums, const float* __restrict__ cnt,
                          const float* __restrict__ Wout, const float* __restrict__ bout,
                          float* __restrict__ y) {
    int g = blockIdx.x;
    int c = threadIdx.x;  // 128 threads
    float v = sums[g * CC + c] / fmaxf(cnt[g], 1.0f) * Wout[c];
#pragma unroll
    for (int off = 32; off > 0; off >>= 1) v += __shfl_down(v, off);
    __shared__ float red[2];
    if ((c & 63) == 0) red[c >> 6] = v;
    __syncthreads();
    if (c == 0) y[g] = red[0] + red[1] + bout[0];
}

extern "C" void kernel_launch(void* const* d_in, const int* in_sizes, int n_in,
                              void* d_out, int out_size, void* d_ws, size_t ws_size,
                              hipStream_t stream) {
    const float* x      = (const float*)d_in[0];
    const int*   eidx   = (const int*)d_in[1];
    const float* ea     = (const float*)d_in[2];
    const int*   batch  = (const int*)d_in[3];
    const float* W_pre  = (const float*)d_in[4];
    const float* b_pre  = (const float*)d_in[5];
    const float* Wf     = (const float*)d_in[6];
    const float* bf     = (const float*)d_in[7];
    const float* Ws     = (const float*)d_in[8];
    const float* bs     = (const float*)d_in[9];
    const float* W_post = (const float*)d_in[10];
    const float* b_post = (const float*)d_in[11];
    const float* W_out  = (const float*)d_in[12];
    const float* b_out  = (const float*)d_in[13];
    float* y = (float*)d_out;

    const int* srcI = eidx;        // edge_index[0] = src (x_j)
    const int* dstI = eidx + EE;   // edge_index[1] = dst (x_i)

    float* P    = (float*)d_ws;                      // N*512
    float* out  = P    + (size_t)NN * 512;           // N*128
    float* agg  = out  + (size_t)NN * CC;            // N*128
    float* WB   = agg  + (size_t)NN * CC;            // 128*512
    float* WT   = WB   + 128 * 512;                  // up to 128*128
    float* sums = WT   + 128 * 128;                  // G*128
    float* cnt  = sums + (size_t)GG * CC;            // G

    int rowTiles = (NN + 63) / 64;

    // pre-FC
    transpose_pad<<<(96 * 128 + 255) / 256, 256, 0, stream>>>(W_pre, WT, CC, FN, 96);
    gemm_rt<1><<<rowTiles * 1, 256, 0, stream>>>(x, WT, out, b_pre, NN, FN, FN, CC);

    for (int l = 0; l < LL; l++) {
        const float* Wfl = Wf + (size_t)l * CC * ZDIM;
        const float* Wsl = Ws + (size_t)l * CC * ZDIM;
        build_WB<<<(128 * 512 + 255) / 256, 256, 0, stream>>>(Wfl, Wsl, WB);
        gemm_rt<0><<<rowTiles * 4, 256, 0, stream>>>(out, WB, P, nullptr, NN, CC, CC, 512);
        hipMemsetAsync(agg, 0, (size_t)NN * CC * sizeof(float), stream);
        edge_gate<<<4096, 256, 0, stream>>>(P, ea, srcI, dstI, Wfl, Wsl,
                                            bf + (size_t)l * CC, bs + (size_t)l * CC, agg);
        residual_softplus<<<(NN * CC / 4 + 255) / 256, 256, 0, stream>>>(out, agg);
    }

    // post-FC (write into P buffer, it's free now)
    transpose_pad<<<(128 * 128 + 255) / 256, 256, 0, stream>>>(W_post, WT, CC, CC, CC);
    float* post = P;
    gemm_rt<1><<<rowTiles * 1, 256, 0, stream>>>(out, WT, post, b_post, NN, CC, CC, CC);

    // global mean pool + head
    hipMemsetAsync(sums, 0, ((size_t)GG * CC + GG) * sizeof(float), stream);
    pool_accum<<<(NN * CC + 255) / 256, 256, 0, stream>>>(post, batch, sums, cnt);
    pool_head<<<GG, 128, 0, stream>>>(sums, cnt, W_out, b_out, y);
}

// Round 2
// 4104.112 us; speedup vs baseline: 1.2703x; 1.2703x over previous
//
#include <hip/hip_runtime.h>
#include <math.h>

#define NN 50000
#define EE 1600000
#define FN 92
#define FE 41
#define CC 128
#define LL 3
#define GG 256
#define ZDIM 297   // 2C + F_EDGE

__device__ __forceinline__ float softplus_f(float x) {
    // max(x,0) + log(1+exp(-|x|)); fast intrinsics (v_exp_f32/v_log_f32)
    float e = __expf(-fabsf(x));
    return fmaxf(x, 0.0f) + __logf(1.0f + e);
}
__device__ __forceinline__ float sigmoid_f(float x) {
    return __builtin_amdgcn_rcpf(1.0f + __expf(-x));
}

// ---------------------------------------------------------------------------
// Generic row-major GEMM: C[M][NC] = act(A[M][lda] (K cols used) @ B[Kpad][NC] + bias)
// Tile: 64 rows x 128 cols, KC=32, block 256 threads, 8x4 micro-tile.
// ---------------------------------------------------------------------------
template<int ACT>
__global__ __launch_bounds__(256)
void gemm_rt(const float* __restrict__ A, const float* __restrict__ B,
             float* __restrict__ C, const float* __restrict__ bias,
             int M, int K, int lda, int NC) {
    __shared__ float As[32][68];     // [k][row], padded
    __shared__ float Bs[32 * 128];   // [k][col]
    int tid = threadIdx.x;
    int colTiles = NC >> 7;
    int rowTile = blockIdx.x / colTiles;
    int colTile = blockIdx.x - rowTile * colTiles;
    int row0 = rowTile * 64;
    int c0 = colTile * 128;
    int ty = tid >> 5;     // 0..7  -> 8 rows each
    int tx = tid & 31;     // 0..31 -> 4 cols each

    float acc[8][4];
#pragma unroll
    for (int i = 0; i < 8; i++)
#pragma unroll
        for (int j = 0; j < 4; j++) acc[i][j] = 0.f;

    int nChunks = (K + 31) >> 5;
    for (int ch = 0; ch < nChunks; ch++) {
        int k0 = ch << 5;
#pragma unroll
        for (int t = 0; t < 8; t++) {
            int idx = tid + t * 256;       // 0..2047
            int r = idx >> 5;              // 0..63
            int kk = idx & 31;
            int grow = row0 + r;
            int gk = k0 + kk;
            float v = 0.f;
            if (grow < M && gk < K) v = A[(long)grow * lda + gk];
            As[kk][r] = v;
        }
        const float* Bg = B + (long)k0 * NC + c0;
#pragma unroll
        for (int t = 0; t < 4; t++) {
            int f4 = tid + t * 256;        // 0..1023
            int kk = f4 >> 5;
            int j = (f4 & 31) << 2;
            float4 v = *(const float4*)(Bg + (long)kk * NC + j);
            *(float4*)(&Bs[kk * 128 + j]) = v;
        }
        __syncthreads();
#pragma unroll
        for (int kk = 0; kk < 32; kk++) {
            float4 a0 = *(const float4*)(&As[kk][ty * 8]);
            float4 a1 = *(const float4*)(&As[kk][ty * 8 + 4]);
            float4 b  = *(const float4*)(&Bs[kk * 128 + tx * 4]);
            float av[8] = {a0.x, a0.y, a0.z, a0.w, a1.x, a1.y, a1.z, a1.w};
            float bv[4] = {b.x, b.y, b.z, b.w};
#pragma unroll
            for (int i = 0; i < 8; i++)
#pragma unroll
                for (int j = 0; j < 4; j++)
                    acc[i][j] = fmaf(av[i], bv[j], acc[i][j]);
        }
        __syncthreads();
    }
    float bv[4] = {0.f, 0.f, 0.f, 0.f};
    if (bias) {
#pragma unroll
        for (int j = 0; j < 4; j++) bv[j] = bias[c0 + tx * 4 + j];
    }
#pragma unroll
    for (int i = 0; i < 8; i++) {
        int grow = row0 + ty * 8 + i;
        if (grow < M) {
            float4 o;
            float r0 = acc[i][0] + bv[0];
            float r1 = acc[i][1] + bv[1];
            float r2 = acc[i][2] + bv[2];
            float r3 = acc[i][3] + bv[3];
            if (ACT) { r0 = softplus_f(r0); r1 = softplus_f(r1);
                       r2 = softplus_f(r2); r3 = softplus_f(r3); }
            o.x = r0; o.y = r1; o.z = r2; o.w = r3;
            *(float4*)(&C[(long)grow * NC + c0 + tx * 4]) = o;
        }
    }
}

// Build WB[128][512]: col j<128: Wf[j][k]; 128..255: Ws[j-128][k];
// 256..383: Wf[j-256][128+k]; 384..511: Ws[j-384][128+k]
__global__ void build_WB(const float* __restrict__ Wf, const float* __restrict__ Ws,
                         float* __restrict__ WB) {
    int idx = blockIdx.x * blockDim.x + threadIdx.x;
    if (idx >= 128 * 512) return;
    int k = idx >> 9;
    int j = idx & 511;
    float v;
    if (j < 128)      v = Wf[j * ZDIM + k];
    else if (j < 256) v = Ws[(j - 128) * ZDIM + k];
    else if (j < 384) v = Wf[(j - 256) * ZDIM + 128 + k];
    else              v = Ws[(j - 384) * ZDIM + 128 + k];
    WB[idx] = v;
}

// WT[Kpad][C] = W[C][K]^T zero-padded in k
__global__ void transpose_pad(const float* __restrict__ W, float* __restrict__ WT,
                              int C_, int K_, int Kpad) {
    int idx = blockIdx.x * blockDim.x + threadIdx.x;
    if (idx >= Kpad * C_) return;
    int k = idx / C_;
    int c = idx - k * C_;
    WT[idx] = (k < K_) ? W[c * K_ + k] : 0.f;
}

// ---------------------------------------------------------------------------
// Edge gate, wave-uniform edge processing:
//   - each half-block (2 waves, channels 0..127) owns one edge stream
//   - edge_attr + indices read via scalar loads (wave-uniform address)
//   - per-channel gate weights live in VGPRs (11x float4 pairs)
// f = P[dst][c] + P[src][256+c] + ea.Wf_e[c] + bf[c]
// s = P[dst][128+c] + P[src][384+c] + ea.Ws_e[c] + bs[c]
// m = sigmoid(f)*softplus(s); agg[dst][c] += m
// ---------------------------------------------------------------------------
__global__ __launch_bounds__(256, 4)
void edge_gate(const float* __restrict__ P, const float* __restrict__ ea,
               const int* __restrict__ srcI, const int* __restrict__ dstI,
               const float* __restrict__ Wf, const float* __restrict__ Ws,
               const float* __restrict__ bf, const float* __restrict__ bs,
               float* __restrict__ agg) {
    const int tid = threadIdx.x;
    const int c = tid & 127;
    const int slot = __builtin_amdgcn_readfirstlane(tid >> 7);  // wave-uniform

    // per-channel edge-weight columns -> VGPRs (small float4 arrays promote)
    float4 wf4[11], ws4[11];
    const float* wfrow = Wf + (size_t)c * ZDIM + 256;
    const float* wsrow = Ws + (size_t)c * ZDIM + 256;
#pragma unroll
    for (int q = 0; q < 11; q++) {
        float4 a, b;
        a.x = (q * 4 + 0 < FE) ? wfrow[q * 4 + 0] : 0.f;
        a.y = (q * 4 + 1 < FE) ? wfrow[q * 4 + 1] : 0.f;
        a.z = (q * 4 + 2 < FE) ? wfrow[q * 4 + 2] : 0.f;
        a.w = (q * 4 + 3 < FE) ? wfrow[q * 4 + 3] : 0.f;
        b.x = (q * 4 + 0 < FE) ? wsrow[q * 4 + 0] : 0.f;
        b.y = (q * 4 + 1 < FE) ? wsrow[q * 4 + 1] : 0.f;
        b.z = (q * 4 + 2 < FE) ? wsrow[q * 4 + 2] : 0.f;
        b.w = (q * 4 + 3 < FE) ? wsrow[q * 4 + 3] : 0.f;
        wf4[q] = a; ws4[q] = b;
    }
    const float bfc = bf[c], bsc = bs[c];

    const long estride = (long)gridDim.x * 2;
    for (long e = (long)blockIdx.x * 2 + slot; e < (long)EE; e += estride) {
        const int d  = __builtin_amdgcn_readfirstlane(dstI[e]);
        const int sv = __builtin_amdgcn_readfirstlane(srcI[e]);
        const float* Pd = P + (size_t)d * 512;
        const float* Ps = P + (size_t)sv * 512 + 256;
        float f = Pd[c] + Ps[c] + bfc;
        float s = Pd[128 + c] + Ps[128 + c] + bsc;
        const float* pe = ea + (size_t)e * FE;   // wave-uniform -> scalar loads
#pragma unroll
        for (int q = 0; q < 11; q++) {
            const float4 a = wf4[q], b = ws4[q];
            if (q * 4 + 0 < FE) { float v = pe[q * 4 + 0]; f = fmaf(v, a.x, f); s = fmaf(v, b.x, s); }
            if (q * 4 + 1 < FE) { float v = pe[q * 4 + 1]; f = fmaf(v, a.y, f); s = fmaf(v, b.y, s); }
            if (q * 4 + 2 < FE) { float v = pe[q * 4 + 2]; f = fmaf(v, a.z, f); s = fmaf(v, b.z, s); }
            if (q * 4 + 3 < FE) { float v = pe[q * 4 + 3]; f = fmaf(v, a.w, f); s = fmaf(v, b.w, s); }
        }
        float m = sigmoid_f(f) * softplus_f(s);
        atomicAdd(&agg[(size_t)d * CC + c], m);
    }
}

__global__ void residual_softplus(float* __restrict__ out, const float* __restrict__ agg) {
    int idx = blockIdx.x * blockDim.x + threadIdx.x;
    if (idx < NN * CC / 4) {
        float4 o = ((const float4*)out)[idx];
        float4 a = ((const float4*)agg)[idx];
        o.x = softplus_f(o.x + a.x);
        o.y = softplus_f(o.y + a.y);
        o.z = softplus_f(o.z + a.z);
        o.w = softplus_f(o.w + a.w);
        ((float4*)out)[idx] = o;
    }
}

__global__ void pool_accum(const float* __restrict__ post, const int* __restrict__ batch,
                           float* __restrict__ sums, float* __restrict__ cnt) {
    int idx = blockIdx.x * blockDim.x + threadIdx.x;
    if (idx >= NN * CC) return;
    int n = idx >> 7;
    int c = idx & 127;
    int g = batch[n];
    atomicAdd(&sums[g * CC + c], post[idx]);
    if (c == 0) atomicAdd(&cnt[g], 1.0f);
}

__global__ void pool_head(const float* __restrict__ sums, const float* __restrict__ cnt,
                          const float* __restrict__ Wout, const float* __restrict__ bout,
                          float* __restrict__ y) {
    int g = blockIdx.x;
    int c = threadIdx.x;  // 128 threads
    float v = sums[g * CC + c] / fmaxf(cnt[g], 1.0f) * Wout[c];
#pragma unroll
    for (int off = 32; off > 0; off >>= 1) v += __shfl_down(v, off);
    __shared__ float red[2];
    if ((c & 63) == 0) red[c >> 6] = v;
    __syncthreads();
    if (c == 0) y[g] = red[0] + red[1] + bout[0];
}

extern "C" void kernel_launch(void* const* d_in, const int* in_sizes, int n_in,
                              void* d_out, int out_size, void* d_ws, size_t ws_size,
                              hipStream_t stream) {
    const float* x      = (const float*)d_in[0];
    const int*   eidx   = (const int*)d_in[1];
    const float* ea     = (const float*)d_in[2];
    const int*   batch  = (const int*)d_in[3];
    const float* W_pre  = (const float*)d_in[4];
    const float* b_pre  = (const float*)d_in[5];
    const float* Wf     = (const float*)d_in[6];
    const float* bf     = (const float*)d_in[7];
    const float* Ws     = (const float*)d_in[8];
    const float* bs     = (const float*)d_in[9];
    const float* W_post = (const float*)d_in[10];
    const float* b_post = (const float*)d_in[11];
    const float* W_out  = (const float*)d_in[12];
    const float* b_out  = (const float*)d_in[13];
    float* y = (float*)d_out;

    const int* srcI = eidx;        // edge_index[0] = src (x_j)
    const int* dstI = eidx + EE;   // edge_index[1] = dst (x_i)

    float* P    = (float*)d_ws;                      // N*512
    float* out  = P    + (size_t)NN * 512;           // N*128
    float* agg  = out  + (size_t)NN * CC;            // N*128
    float* WB   = agg  + (size_t)NN * CC;            // 128*512
    float* WT   = WB   + 128 * 512;                  // up to 128*128
    float* sums = WT   + 128 * 128;                  // G*128
    float* cnt  = sums + (size_t)GG * CC;            // G

    int rowTiles = (NN + 63) / 64;

    // pre-FC
    transpose_pad<<<(96 * 128 + 255) / 256, 256, 0, stream>>>(W_pre, WT, CC, FN, 96);
    gemm_rt<1><<<rowTiles * 1, 256, 0, stream>>>(x, WT, out, b_pre, NN, FN, FN, CC);

    for (int l = 0; l < LL; l++) {
        const float* Wfl = Wf + (size_t)l * CC * ZDIM;
        const float* Wsl = Ws + (size_t)l * CC * ZDIM;
        build_WB<<<(128 * 512 + 255) / 256, 256, 0, stream>>>(Wfl, Wsl, WB);
        gemm_rt<0><<<rowTiles * 4, 256, 0, stream>>>(out, WB, P, nullptr, NN, CC, CC, 512);
        hipMemsetAsync(agg, 0, (size_t)NN * CC * sizeof(float), stream);
        edge_gate<<<1024, 256, 0, stream>>>(P, ea, srcI, dstI, Wfl, Wsl,
                                            bf + (size_t)l * CC, bs + (size_t)l * CC, agg);
        residual_softplus<<<(NN * CC / 4 + 255) / 256, 256, 0, stream>>>(out, agg);
    }

    // post-FC (write into P buffer, it's free now)
    transpose_pad<<<(128 * 128 + 255) / 256, 256, 0, stream>>>(W_post, WT, CC, CC, CC);
    float* post = P;
    gemm_rt<1><<<rowTiles * 1, 256, 0, stream>>>(out, WT, post, b_post, NN, CC, CC, CC);

    // global mean pool + head
    hipMemsetAsync(sums, 0, ((size_t)GG * CC + GG) * sizeof(float), stream);
    pool_accum<<<(NN * CC + 255) / 256, 256, 0, stream>>>(post, batch, sums, cnt);
    pool_head<<<GG, 128, 0, stream>>>(sums, cnt, W_out, b_out, y);
}

// Round 3
// 3550.506 us; speedup vs baseline: 1.4684x; 1.1559x over previous
//
#include <hip/hip_runtime.h>
#include <math.h>

#define NN 50000
#define EE 1600000
#define FN 92
#define FE 41
#define CC 128
#define LL 3
#define GG 256
#define ZDIM 297   // 2C + F_EDGE

typedef __attribute__((ext_vector_type(8))) short s8v;   // 8 bf16 (4 VGPRs)
typedef __attribute__((ext_vector_type(4))) float f4v;   // MFMA C/D

__device__ __forceinline__ float softplus_f(float x) {
    float e = __expf(-fabsf(x));
    return fmaxf(x, 0.0f) + __logf(1.0f + e);
}
__device__ __forceinline__ float sigmoid_f(float x) {
    return __builtin_amdgcn_rcpf(1.0f + __expf(-x));
}
__device__ __forceinline__ unsigned short f2bf(float x) {   // RNE fp32->bf16
    unsigned u = __builtin_bit_cast(unsigned, x);
    unsigned r = u + 0x7fffu + ((u >> 16) & 1u);
    return (unsigned short)(r >> 16);
}
__device__ __forceinline__ float bflo2f(unsigned u) {  // low ushort as bf16
    return __builtin_bit_cast(float, u << 16);
}
__device__ __forceinline__ float bfhi2f(unsigned u) {  // high ushort as bf16
    return __builtin_bit_cast(float, u & 0xffff0000u);
}

// ---------------------------------------------------------------------------
// fp32 tiled GEMM: C = act(A[M][lda](K used) @ B[Kpad][NC] + bias)
// OUTBF=1: write bf16 (pairs of adjacent columns packed into uint) to C.
// ---------------------------------------------------------------------------
template<int ACT, int OUTBF>
__global__ __launch_bounds__(256)
void gemm_rt(const float* __restrict__ A, const float* __restrict__ B,
             float* __restrict__ C, const float* __restrict__ bias,
             int M, int K, int lda, int NC) {
    __shared__ float As[32][68];
    __shared__ float Bs[32 * 128];
    int tid = threadIdx.x;
    int colTiles = NC >> 7;
    int rowTile = blockIdx.x / colTiles;
    int colTile = blockIdx.x - rowTile * colTiles;
    int row0 = rowTile * 64;
    int c0 = colTile * 128;
    int ty = tid >> 5;
    int tx = tid & 31;

    float acc[8][4];
#pragma unroll
    for (int i = 0; i < 8; i++)
#pragma unroll
        for (int j = 0; j < 4; j++) acc[i][j] = 0.f;

    int nChunks = (K + 31) >> 5;
    for (int ch = 0; ch < nChunks; ch++) {
        int k0 = ch << 5;
#pragma unroll
        for (int t = 0; t < 8; t++) {
            int idx = tid + t * 256;
            int r = idx >> 5;
            int kk = idx & 31;
            int grow = row0 + r;
            int gk = k0 + kk;
            float v = 0.f;
            if (grow < M && gk < K) v = A[(long)grow * lda + gk];
            As[kk][r] = v;
        }
        const float* Bg = B + (long)k0 * NC + c0;
#pragma unroll
        for (int t = 0; t < 4; t++) {
            int f4 = tid + t * 256;
            int kk = f4 >> 5;
            int j = (f4 & 31) << 2;
            float4 v = *(const float4*)(Bg + (long)kk * NC + j);
            *(float4*)(&Bs[kk * 128 + j]) = v;
        }
        __syncthreads();
#pragma unroll
        for (int kk = 0; kk < 32; kk++) {
            float4 a0 = *(const float4*)(&As[kk][ty * 8]);
            float4 a1 = *(const float4*)(&As[kk][ty * 8 + 4]);
            float4 b  = *(const float4*)(&Bs[kk * 128 + tx * 4]);
            float av[8] = {a0.x, a0.y, a0.z, a0.w, a1.x, a1.y, a1.z, a1.w};
            float bv[4] = {b.x, b.y, b.z, b.w};
#pragma unroll
            for (int i = 0; i < 8; i++)
#pragma unroll
                for (int j = 0; j < 4; j++)
                    acc[i][j] = fmaf(av[i], bv[j], acc[i][j]);
        }
        __syncthreads();
    }
    float bv[4] = {0.f, 0.f, 0.f, 0.f};
    if (bias) {
#pragma unroll
        for (int j = 0; j < 4; j++) bv[j] = bias[c0 + tx * 4 + j];
    }
#pragma unroll
    for (int i = 0; i < 8; i++) {
        int grow = row0 + ty * 8 + i;
        if (grow < M) {
            float r0 = acc[i][0] + bv[0];
            float r1 = acc[i][1] + bv[1];
            float r2 = acc[i][2] + bv[2];
            float r3 = acc[i][3] + bv[3];
            if (ACT) { r0 = softplus_f(r0); r1 = softplus_f(r1);
                       r2 = softplus_f(r2); r3 = softplus_f(r3); }
            if (OUTBF) {
                unsigned u0 = (unsigned)f2bf(r0) | ((unsigned)f2bf(r1) << 16);
                unsigned u1 = (unsigned)f2bf(r2) | ((unsigned)f2bf(r3) << 16);
                uint2 val; val.x = u0; val.y = u1;
                unsigned short* Cb = (unsigned short*)C;
                *(uint2*)(Cb + (long)grow * NC + c0 + tx * 4) = val;
            } else {
                float4 o; o.x = r0; o.y = r1; o.z = r2; o.w = r3;
                *(float4*)(&C[(long)grow * NC + c0 + tx * 4]) = o;
            }
        }
    }
}

// WB[k][j], j=0..511: g=j&1 (0=f/Wf, 1=s/Ws); pos=j>>1; blk=pos>>7 (0=dst->x_i
// cols 0..127, 1=src->x_j cols 128..255); c=pos&127.
__global__ void build_WB(const float* __restrict__ Wf, const float* __restrict__ Ws,
                         float* __restrict__ WB) {
    int idx = blockIdx.x * blockDim.x + threadIdx.x;
    if (idx >= 128 * 512) return;
    int k = idx >> 9;
    int j = idx & 511;
    int g = j & 1;
    int pos = j >> 1;
    int blk = pos >> 7;
    int c = pos & 127;
    const float* W = g ? Ws : Wf;
    WB[idx] = W[c * ZDIM + blk * 128 + k];
}

// WE[l][g][c][k] bf16, k<41: edge-weight col, k==41: bias, else 0. K padded to 64.
__global__ void build_WE(const float* __restrict__ Wf, const float* __restrict__ Ws,
                         const float* __restrict__ bf, const float* __restrict__ bs,
                         unsigned short* __restrict__ WE) {
    int idx = blockIdx.x * blockDim.x + threadIdx.x;
    if (idx >= LL * 2 * 128 * 64) return;
    int k = idx & 63;
    int c = (idx >> 6) & 127;
    int g = (idx >> 13) & 1;
    int l = idx >> 14;
    const float* W = g ? Ws : Wf;
    const float* b = g ? bs : bf;
    float v = 0.f;
    if (k < FE) v = W[((long)l * 128 + c) * ZDIM + 256 + k];
    else if (k == FE) v = b[l * 128 + c];
    WE[idx] = f2bf(v);
}

// WT[Kpad][C] = W[C][K]^T zero-padded
__global__ void transpose_pad(const float* __restrict__ W, float* __restrict__ WT,
                              int C_, int K_, int Kpad) {
    int idx = blockIdx.x * blockDim.x + threadIdx.x;
    if (idx >= Kpad * C_) return;
    int k = idx / C_;
    int c = idx - k * C_;
    WT[idx] = (k < K_) ? W[c * K_ + k] : 0.f;
}

// ---------------------------------------------------------------------------
// Fused edge kernel. Each wave: 16 consecutive edges.
//  Phase 1: Qf,Qs = [16x48 ea+bias] @ WE^T via 32 MFMAs (B frags L1-resident).
//  Phase 2: gate in registers using MFMA D layout (col=lane&15=channel,
//           row=quad*4+reg=edge), gather bf16 P pairs, atomic scatter.
// ---------------------------------------------------------------------------
__global__ __launch_bounds__(256, 3)
void edge_fused(const unsigned* __restrict__ Pu,             // [N][256] uint pairs
                const float* __restrict__ ea,
                const int* __restrict__ srcI, const int* __restrict__ dstI,
                const unsigned short* __restrict__ WE,       // [2][128][64] this layer
                float* __restrict__ agg) {
    const int lane = threadIdx.x & 63;
    const int waveInBlk = threadIdx.x >> 6;
    const int quad = lane >> 4;
    const int l16 = lane & 15;
    const long nWaves = (long)gridDim.x * 4;
    const int NCHUNK = EE / 16;
    const unsigned short* WEf = WE;
    const unsigned short* WEs = WE + 128 * 64;

    for (long chk = (long)blockIdx.x * 4 + waveInBlk; chk < NCHUNK; chk += nWaves) {
        const long e0 = chk * 16;
        int d16 = dstI[e0 + l16];
        int s16 = srcI[e0 + l16];

        // A fragments from fp32 ea, on-the-fly bf16, bias col at k=41
        const float* ar = ea + (e0 + l16) * (long)FE;
        s8v a0, a1;
#pragma unroll
        for (int j = 0; j < 8; j++) {
            a0[j] = (short)f2bf(ar[quad * 8 + j]);           // k=0..31, all real
        }
#pragma unroll
        for (int j = 0; j < 8; j++) {
            int k1 = 32 + quad * 8 + j;
            float v = 0.f;
            if (k1 < FE) v = ar[k1];
            else if (k1 == FE) v = 1.0f;
            a1[j] = (short)f2bf(v);
        }

        f4v accf[8], accs[8];
#pragma unroll
        for (int nt = 0; nt < 8; nt++) {
            int crow = nt * 16 + l16;
            s8v bf0 = *(const s8v*)(WEf + crow * 64 + quad * 8);
            s8v bf1 = *(const s8v*)(WEf + crow * 64 + 32 + quad * 8);
            f4v z = {0.f, 0.f, 0.f, 0.f};
            z = __builtin_amdgcn_mfma_f32_16x16x32_bf16(a0, bf0, z, 0, 0, 0);
            z = __builtin_amdgcn_mfma_f32_16x16x32_bf16(a1, bf1, z, 0, 0, 0);
            accf[nt] = z;
            s8v bs0 = *(const s8v*)(WEs + crow * 64 + quad * 8);
            s8v bs1 = *(const s8v*)(WEs + crow * 64 + 32 + quad * 8);
            f4v z2 = {0.f, 0.f, 0.f, 0.f};
            z2 = __builtin_amdgcn_mfma_f32_16x16x32_bf16(a0, bs0, z2, 0, 0, 0);
            z2 = __builtin_amdgcn_mfma_f32_16x16x32_bf16(a1, bs1, z2, 0, 0, 0);
            accs[nt] = z2;
        }

#pragma unroll
        for (int r = 0; r < 4; r++) {
            int el = quad * 4 + r;                 // edge row in D layout
            int dv = __shfl(d16, el);
            int sv = __shfl(s16, el);
            const unsigned* pd_base = Pu + (long)dv * 256;
            const unsigned* ps_base = Pu + (long)sv * 256 + 128;
            float* ag = agg + (long)dv * CC;
#pragma unroll
            for (int nt = 0; nt < 8; nt++) {
                int c = nt * 16 + l16;
                unsigned pd = pd_base[c];
                unsigned ps = ps_base[c];
                float f = accf[nt][r] + bflo2f(pd) + bflo2f(ps);
                float s = accs[nt][r] + bfhi2f(pd) + bfhi2f(ps);
                float m = sigmoid_f(f) * softplus_f(s);
                atomicAdd(&ag[c], m);
            }
        }
    }
}

__global__ void residual_softplus(float* __restrict__ out, const float* __restrict__ agg) {
    int idx = blockIdx.x * blockDim.x + threadIdx.x;
    if (idx < NN * CC / 4) {
        float4 o = ((const float4*)out)[idx];
        float4 a = ((const float4*)agg)[idx];
        o.x = softplus_f(o.x + a.x);
        o.y = softplus_f(o.y + a.y);
        o.z = softplus_f(o.z + a.z);
        o.w = softplus_f(o.w + a.w);
        ((float4*)out)[idx] = o;
    }
}

__global__ void pool_accum(const float* __restrict__ post, const int* __restrict__ batch,
                           float* __restrict__ sums, float* __restrict__ cnt) {
    int idx = blockIdx.x * blockDim.x + threadIdx.x;
    if (idx >= NN * CC) return;
    int n = idx >> 7;
    int c = idx & 127;
    int g = batch[n];
    atomicAdd(&sums[g * CC + c], post[idx]);
    if (c == 0) atomicAdd(&cnt[g], 1.0f);
}

__global__ void pool_head(const float* __restrict__ sums, const float* __restrict__ cnt,
                          const float* __restrict__ Wout, const float* __restrict__ bout,
                          float* __restrict__ y) {
    int g = blockIdx.x;
    int c = threadIdx.x;  // 128
    float v = sums[g * CC + c] / fmaxf(cnt[g], 1.0f) * Wout[c];
#pragma unroll
    for (int off = 32; off > 0; off >>= 1) v += __shfl_down(v, off);
    __shared__ float red[2];
    if ((c & 63) == 0) red[c >> 6] = v;
    __syncthreads();
    if (c == 0) y[g] = red[0] + red[1] + bout[0];
}

extern "C" void kernel_launch(void* const* d_in, const int* in_sizes, int n_in,
                              void* d_out, int out_size, void* d_ws, size_t ws_size,
                              hipStream_t stream) {
    const float* x      = (const float*)d_in[0];
    const int*   eidx   = (const int*)d_in[1];
    const float* ea     = (const float*)d_in[2];
    const int*   batch  = (const int*)d_in[3];
    const float* W_pre  = (const float*)d_in[4];
    const float* b_pre  = (const float*)d_in[5];
    const float* Wf     = (const float*)d_in[6];
    const float* bf     = (const float*)d_in[7];
    const float* Ws     = (const float*)d_in[8];
    const float* bs     = (const float*)d_in[9];
    const float* W_post = (const float*)d_in[10];
    const float* b_post = (const float*)d_in[11];
    const float* W_out  = (const float*)d_in[12];
    const float* b_out  = (const float*)d_in[13];
    float* y = (float*)d_out;

    const int* srcI = eidx;        // edge_index[0] = src (x_j)
    const int* dstI = eidx + EE;   // edge_index[1] = dst (x_i)

    // workspace layout
    unsigned short* P_bf = (unsigned short*)d_ws;            // N*512 bf16 = 51.2MB
    float* out  = (float*)(P_bf + (size_t)NN * 512);         // N*128
    float* agg  = out + (size_t)NN * CC;                     // N*128
    float* WB   = agg + (size_t)NN * CC;                     // 128*512
    float* WT   = WB + 128 * 512;                            // 128*128
    float* sums = WT + 128 * 128;                            // G*128
    float* cnt  = sums + (size_t)GG * CC;                    // G
    unsigned short* WE = (unsigned short*)(cnt + GG);        // 3*2*128*64
    float* post = (float*)P_bf;                              // reuse after layers

    int rowTiles = (NN + 63) / 64;

    // pre-FC
    transpose_pad<<<(96 * 128 + 255) / 256, 256, 0, stream>>>(W_pre, WT, CC, FN, 96);
    gemm_rt<1, 0><<<rowTiles, 256, 0, stream>>>(x, WT, out, b_pre, NN, FN, FN, CC);

    build_WE<<<(LL * 2 * 128 * 64 + 255) / 256, 256, 0, stream>>>(Wf, Ws, bf, bs, WE);

    for (int l = 0; l < LL; l++) {
        const float* Wfl = Wf + (size_t)l * CC * ZDIM;
        const float* Wsl = Ws + (size_t)l * CC * ZDIM;
        build_WB<<<(128 * 512 + 255) / 256, 256, 0, stream>>>(Wfl, Wsl, WB);
        gemm_rt<0, 1><<<rowTiles * 4, 256, 0, stream>>>(out, WB, (float*)P_bf,
                                                        nullptr, NN, CC, CC, 512);
        hipMemsetAsync(agg, 0, (size_t)NN * CC * sizeof(float), stream);
        edge_fused<<<2048, 256, 0, stream>>>((const unsigned*)P_bf, ea, srcI, dstI,
                                             WE + (size_t)l * 2 * 128 * 64, agg);
        residual_softplus<<<(NN * CC / 4 + 255) / 256, 256, 0, stream>>>(out, agg);
    }

    // post-FC
    transpose_pad<<<(128 * 128 + 255) / 256, 256, 0, stream>>>(W_post, WT, CC, CC, CC);
    gemm_rt<1, 0><<<rowTiles, 256, 0, stream>>>(out, WT, post, b_post, NN, CC, CC, CC);

    // global mean pool + head
    hipMemsetAsync(sums, 0, ((size_t)GG * CC + GG) * sizeof(float), stream);
    pool_accum<<<(NN * CC + 255) / 256, 256, 0, stream>>>(post, batch, sums, cnt);
    pool_head<<<GG, 128, 0, stream>>>(sums, cnt, W_out, b_out, y);
}